// Round 1
// baseline (1422.134 us; speedup 1.0000x reference)
//
#include <hip/hip_runtime.h>
#include <math.h>

// ---------------------------------------------------------------------------
// Bidirectional Mamba block, MI355X. Round 0: all-f32, fused scan.
// Buffers in ws (f32 elements):
//   xz    [b][4096][1024]           8,388,608
//   u     [dir*2+b][2048][1024]     8,388,608
//   xdbl  [dir*2+b][96][1024]         393,216
//   delta [dir*2+b][2048][1024]     8,388,608   (raw, pre-bias/softplus)
//   y     [dir*2+b][2048][1024]     8,388,608
//   G  aliases delta after scan     (4,194,304 used)
// total ~136 MB
// ---------------------------------------------------------------------------

// Generic f32 tiled GEMM. A: MxK row-major (K-contig).
// B_NK ? B is NxK row-major (K-contig)  : B is KxN row-major (N-contig).
// CT   ? C[n*M + m] (transposed store)  : C[m*N + n].
template<int BM, int BN, int TM, int TN, bool B_NK, bool CT>
__global__ __launch_bounds__(256)
void gemm_f32(const float* __restrict__ A, const float* __restrict__ B,
              float* __restrict__ C, int M, int N, int K,
              long sA, long sB, long sC)
{
    constexpr int BK = 16;
    __shared__ float As[BK][BM + 4];
    __shared__ float Bs[BK][BN + 4];
    A += (long)blockIdx.z * sA;
    B += (long)blockIdx.z * sB;
    C += (long)blockIdx.z * sC;
    const int m0 = blockIdx.y * BM;
    const int n0 = blockIdx.x * BN;
    const int t  = threadIdx.x;
    const int tx = t % (BN / TN);
    const int ty = t / (BN / TN);
    float acc[TM][TN];
#pragma unroll
    for (int i = 0; i < TM; ++i)
#pragma unroll
        for (int j = 0; j < TN; ++j) acc[i][j] = 0.f;

    for (int k0 = 0; k0 < K; k0 += BK) {
        constexpr int A_IT = BM * BK / 4 / 256;
#pragma unroll
        for (int i = 0; i < A_IT; ++i) {
            int idx = t + i * 256;
            int m = idx >> 2, kq = idx & 3;
            float4 v = make_float4(0.f, 0.f, 0.f, 0.f);
            if (m0 + m < M)
                v = *(const float4*)&A[(long)(m0 + m) * K + k0 + kq * 4];
            As[kq * 4 + 0][m] = v.x;
            As[kq * 4 + 1][m] = v.y;
            As[kq * 4 + 2][m] = v.z;
            As[kq * 4 + 3][m] = v.w;
        }
        constexpr int B_IT = BN * BK / 4 / 256;
        if constexpr (B_NK) {
#pragma unroll
            for (int i = 0; i < B_IT; ++i) {
                int idx = t + i * 256;
                int n = idx >> 2, kq = idx & 3;
                float4 v = *(const float4*)&B[(long)(n0 + n) * K + k0 + kq * 4];
                Bs[kq * 4 + 0][n] = v.x;
                Bs[kq * 4 + 1][n] = v.y;
                Bs[kq * 4 + 2][n] = v.z;
                Bs[kq * 4 + 3][n] = v.w;
            }
        } else {
#pragma unroll
            for (int i = 0; i < B_IT; ++i) {
                int idx = t + i * 256;
                int k = idx / (BN / 4), q = idx % (BN / 4);
                float4 v = *(const float4*)&B[(long)(k0 + k) * N + n0 + q * 4];
                *(float4*)&Bs[k][q * 4] = v;
            }
        }
        __syncthreads();
#pragma unroll
        for (int k = 0; k < BK; ++k) {
            float a[TM], bb[TN];
#pragma unroll
            for (int i = 0; i < TM; i += 4) {
                float4 v = *(const float4*)&As[k][ty * TM + i];
                a[i] = v.x; a[i + 1] = v.y; a[i + 2] = v.z; a[i + 3] = v.w;
            }
#pragma unroll
            for (int j = 0; j < TN; j += 4) {
                float4 v = *(const float4*)&Bs[k][tx * TN + j];
                bb[j] = v.x; bb[j + 1] = v.y; bb[j + 2] = v.z; bb[j + 3] = v.w;
            }
#pragma unroll
            for (int i = 0; i < TM; ++i)
#pragma unroll
                for (int j = 0; j < TN; ++j)
                    acc[i][j] = fmaf(a[i], bb[j], acc[i][j]);
        }
        __syncthreads();
    }
#pragma unroll
    for (int i = 0; i < TM; ++i) {
        int m = m0 + ty * TM + i;
        if (m >= M) continue;
        if constexpr (!CT) {
#pragma unroll
            for (int j = 0; j < TN; j += 4) {
                float4 v = make_float4(acc[i][j], acc[i][j + 1], acc[i][j + 2], acc[i][j + 3]);
                *(float4*)&C[(long)m * N + n0 + tx * TN + j] = v;
            }
        } else {
#pragma unroll
            for (int j = 0; j < TN; ++j)
                C[(long)(n0 + tx * TN + j) * M + m] = acc[i][j];
        }
    }
}

// Depthwise causal conv (k=4) + SiLU, both directions.
// Backward direction computed & stored in reversed-lambda coordinates.
__global__ __launch_bounds__(256)
void conv_silu_kernel(const float* __restrict__ xz,
                      const float* __restrict__ wf, const float* __restrict__ bf,
                      const float* __restrict__ wb, const float* __restrict__ bbk,
                      float* __restrict__ u)
{
    long idx = (long)blockIdx.x * 256 + threadIdx.x;   // (dir,b,d,l)
    int l = (int)(idx & 1023);
    long r = idx >> 10;
    int d = (int)(r & 2047);
    int b = (int)((r >> 11) & 1);
    int dir = (int)(r >> 12);
    const float* x = xz + ((long)b * 4096 + d) * 1024;
    const float* w = dir ? wb : wf;
    float s = dir ? bbk[d] : bf[d];
    if (dir == 0) {
#pragma unroll
        for (int j = 0; j < 4; ++j) {
            int p = l - 3 + j;
            if (p >= 0) s = fmaf(w[d * 4 + j], x[p], s);
        }
    } else {
#pragma unroll
        for (int j = 0; j < 4; ++j) {
            int src = l - 3 + j;               // index in reversed sequence
            if (src >= 0) s = fmaf(w[d * 4 + j], x[1023 - src], s);
        }
    }
    u[idx] = s / (1.f + expf(-s));             // silu
}

// Fused selective scan. Block = 256 threads = 16 d-groups x 16 n-lanes.
// Each thread holds scalar recurrence h for its (d,n); y reduced over n.
__global__ __launch_bounds__(256)
void scan_kernel(const float* __restrict__ u,      // [dirb][2048][1024]
                 const float* __restrict__ delta,  // [dirb][2048][1024] raw
                 const float* __restrict__ xdbl,   // [dirb][96][1024]
                 const float* __restrict__ dtbf, const float* __restrict__ dtbb,
                 const float* __restrict__ Alf, const float* __restrict__ Alb,
                 const float* __restrict__ Df, const float* __restrict__ Db,
                 float* __restrict__ y)            // [dirb][2048][1024]
{
    const int n  = threadIdx.x & 15;
    const int dg = threadIdx.x >> 4;
    const int d0 = blockIdx.x * 16;
    const int b = blockIdx.y, dir = blockIdx.z;
    const int dirb = dir * 2 + b;
    const int d = d0 + dg;
    const float* Alog = dir ? Alb : Alf;
    const float Adn  = -expf(Alog[d * 16 + n]);
    const float bias = (dir ? dtbb : dtbf)[d];
    const float Dd   = (dir ? Db : Df)[d];
    const float* ub = u     + ((long)dirb * 2048 + d0) * 1024;
    const float* db = delta + ((long)dirb * 2048 + d0) * 1024;
    const float* Bb = xdbl  + ((long)dirb * 96 + 64) * 1024;
    const float* Cb = xdbl  + ((long)dirb * 96 + 80) * 1024;
    float* yb = y + ((long)dirb * 2048 + d0) * 1024;

    __shared__ float sD[16][68], sU[16][68], sB[16][68], sC[16][68], sY[16][68];
    float h = 0.f;
    const int dd = threadIdx.x >> 4, q = threadIdx.x & 15;
    for (int l0 = 0; l0 < 1024; l0 += 64) {
        *(float4*)&sD[dd][q * 4] = *(const float4*)&db[dd * 1024 + l0 + q * 4];
        *(float4*)&sU[dd][q * 4] = *(const float4*)&ub[dd * 1024 + l0 + q * 4];
        *(float4*)&sB[dd][q * 4] = *(const float4*)&Bb[dd * 1024 + l0 + q * 4];
        *(float4*)&sC[dd][q * 4] = *(const float4*)&Cb[dd * 1024 + l0 + q * 4];
        __syncthreads();
#pragma unroll 4
        for (int l = 0; l < 64; ++l) {
            float dr = sD[dg][l] + bias;
            float dl = (dr > 20.f) ? dr : log1pf(expf(dr));   // softplus
            float uu = sU[dg][l];
            float dA = expf(dl * Adn);
            float dBx = dl * sB[n][l] * uu;
            h = fmaf(dA, h, dBx);
            float yc = h * sC[n][l];
            yc += __shfl_xor(yc, 1);
            yc += __shfl_xor(yc, 2);
            yc += __shfl_xor(yc, 4);
            yc += __shfl_xor(yc, 8);
            if (n == 0) sY[dg][l] = fmaf(Dd, uu, yc);
        }
        __syncthreads();
        *(float4*)&yb[dd * 1024 + l0 + q * 4] = *(const float4*)&sY[dd][q * 4];
        __syncthreads();
    }
}

// G[b,d,l] = silu(z[b,d,l]) * (y_f[b,d,l] + y_b[b,d,1023-l])
__global__ __launch_bounds__(256)
void combine_kernel(const float* __restrict__ xz, const float* __restrict__ y,
                    float* __restrict__ G)
{
    long idx = (long)blockIdx.x * 256 + threadIdx.x;   // (b,d,l)
    int l = (int)(idx & 1023);
    long r = idx >> 10;
    int d = (int)(r & 2047);
    int b = (int)(r >> 11);
    float z  = xz[((long)b * 4096 + 2048 + d) * 1024 + l];
    float yf = y[((long)(0 * 2 + b) * 2048 + d) * 1024 + l];
    float yv = y[((long)(1 * 2 + b) * 2048 + d) * 1024 + (1023 - l)];
    float sz = z / (1.f + expf(-z));
    G[idx] = sz * (yf + yv);
}

extern "C" void kernel_launch(void* const* d_in, const int* in_sizes, int n_in,
                              void* d_out, int out_size, void* d_ws, size_t ws_size,
                              hipStream_t stream)
{
    const float* hidden   = (const float*)d_in[0];
    const float* inproj_w = (const float*)d_in[1];
    const float* conv_w   = (const float*)d_in[2];
    const float* conv_b   = (const float*)d_in[3];
    const float* xproj_w  = (const float*)d_in[4];
    const float* dtproj_w = (const float*)d_in[5];
    const float* dt_bias  = (const float*)d_in[6];
    const float* A_log    = (const float*)d_in[7];
    const float* D_skip   = (const float*)d_in[8];
    const float* convb_w  = (const float*)d_in[9];
    const float* convb_b  = (const float*)d_in[10];
    const float* xprojb_w = (const float*)d_in[11];
    const float* dtprojb_w= (const float*)d_in[12];
    const float* dtb_bias = (const float*)d_in[13];
    const float* Ab_log   = (const float*)d_in[14];
    const float* Db_skip  = (const float*)d_in[15];
    const float* outproj_w= (const float*)d_in[16];
    float* out = (float*)d_out;

    float* ws    = (float*)d_ws;
    float* xz    = ws;                      // 8,388,608
    float* u     = ws + 8388608;            // 8,388,608
    float* xdbl  = ws + 16777216;           //   393,216
    float* delta = ws + 17170432;           // 8,388,608
    float* y     = ws + 25559040;           // 8,388,608
    float* G     = delta;                   // alias (delta dead after scan)

    // 1) in_proj: xz[b,e,l] = sum_d W[e,d]*hidden[b,l,d]
    hipLaunchKernelGGL((gemm_f32<128, 128, 8, 8, true, false>),
        dim3(8, 32, 2), dim3(256), 0, stream,
        inproj_w, hidden, xz, 4096, 1024, 1024,
        0L, (long)1024 * 1024, (long)4096 * 1024);

    // 2) conv + silu, both directions
    hipLaunchKernelGGL(conv_silu_kernel, dim3(32768), dim3(256), 0, stream,
        xz, conv_w, conv_b, convb_w, convb_b, u);

    // 3) x_proj per direction: xdbl[k,l] = sum_d W[k,d]*u[d,l]
    for (int dir = 0; dir < 2; ++dir) {
        hipLaunchKernelGGL((gemm_f32<64, 128, 4, 8, false, false>),
            dim3(8, 2, 2), dim3(256), 0, stream,
            dir ? xprojb_w : xproj_w,
            u + (long)dir * 2 * 2048 * 1024,
            xdbl + (long)dir * 2 * 96 * 1024,
            96, 1024, 2048,
            0L, (long)2048 * 1024, (long)96 * 1024);
    }

    // 4) dt_proj per direction: delta[d,l] = sum_r W[d,r]*xdbl[r,l]
    for (int dir = 0; dir < 2; ++dir) {
        hipLaunchKernelGGL((gemm_f32<128, 128, 8, 8, false, false>),
            dim3(8, 16, 2), dim3(256), 0, stream,
            dir ? dtprojb_w : dtproj_w,
            xdbl + (long)dir * 2 * 96 * 1024,
            delta + (long)dir * 2 * 2048 * 1024,
            2048, 1024, 64,
            0L, (long)96 * 1024, (long)2048 * 1024);
    }

    // 5) fused selective scan (softplus, dA, recurrence, y = h.C + D*u)
    hipLaunchKernelGGL(scan_kernel, dim3(128, 2, 2), dim3(256), 0, stream,
        u, delta, xdbl, dt_bias, dtb_bias, A_log, Ab_log, D_skip, Db_skip, y);

    // 6) combine: G = silu(z) * (y_f + reversed y_b)
    hipLaunchKernelGGL(combine_kernel, dim3(16384), dim3(256), 0, stream,
        xz, y, G);

    // 7) out_proj: out[b,l,o] = sum_d W[o,d]*G[b,d,l]  (transposed store)
    hipLaunchKernelGGL((gemm_f32<64, 128, 4, 8, false, true>),
        dim3(8, 16, 2), dim3(256), 0, stream,
        outproj_w, G, out, 1024, 1024, 2048,
        0L, (long)2048 * 1024, (long)1024 * 1024);
}

// Round 6
// 650.016 us; speedup vs baseline: 2.1878x; 2.1878x over previous
//
#include <hip/hip_runtime.h>
#include <math.h>

// ---------------------------------------------------------------------------
// Bidirectional Mamba block, MI355X. Round 5 (= round 2 resubmit; infra fail x3):
//  - FIX: DPP reduce used row_shr (sum lands in TOP lane, lane0 had only a
//    quad partial -> dropped states 4..15). Replaced with row_half_mirror +
//    row_mirror butterfly: full sum in ALL 16 lanes, direction-proof.
//  - kept: softplus fused in dt_proj epilogue, batched x/dt_proj GEMMs,
//    float4 CT store in out_proj, exp2-based transcendentals.
// ws layout (f32 elements):
//   xz    [b][4096][1024]           8,388,608
//   u     [dirb][2048][1024]        8,388,608
//   xdbl  [dirb][96][1024]            393,216
//   delta [dirb][2048][1024]        8,388,608   (post-softplus)
//   y     [dirb][2048][1024]        8,388,608   (head doubles as weight-concat
//                                                scratch, dead before scan)
// ---------------------------------------------------------------------------

__device__ __forceinline__ float softplus_f(float x) {
    float e = __builtin_amdgcn_exp2f(-fabsf(x) * 1.44269504f);
    return fmaxf(x, 0.f) + __builtin_amdgcn_logf(1.f + e) * 0.69314718f;
}

template<int CTRL>
__device__ __forceinline__ float dpp_add(float x) {
    int s = __builtin_amdgcn_update_dpp(0, __builtin_bit_cast(int, x),
                                        CTRL, 0xF, 0xF, true);
    return x + __builtin_bit_cast(float, s);
}

// Generic f32 tiled GEMM. A: MxK row-major (K-contig).
// B_NK ? B is NxK row-major : B is KxN row-major.
// CT   ? C[n*M + m] (transposed store, float4 over m)  : C[m*N + n].
// AHALF? A advances by sA every 2 z-slices (dir = z>>1).
// SP   ? epilogue v = softplus(v + bias[m]) with bias batched per dir.
template<int BM, int BN, int TM, int TN, bool B_NK, bool CT, bool AHALF, bool SP>
__global__ __launch_bounds__(256)
void gemm_f32(const float* __restrict__ A, const float* __restrict__ B,
              float* __restrict__ C, int M, int N, int K,
              long sA, long sB, long sC, const float* __restrict__ bias)
{
    constexpr int BK = 16;
    __shared__ float As[BK][BM + 4];
    __shared__ float Bs[BK][BN + 4];
    A += (AHALF ? (long)(blockIdx.z >> 1) : (long)blockIdx.z) * sA;
    B += (long)blockIdx.z * sB;
    C += (long)blockIdx.z * sC;
    if constexpr (SP) bias += (long)(blockIdx.z >> 1) * M;
    const int m0 = blockIdx.y * BM;
    const int n0 = blockIdx.x * BN;
    const int t  = threadIdx.x;
    const int tx = t % (BN / TN);
    const int ty = t / (BN / TN);
    float acc[TM][TN];
#pragma unroll
    for (int i = 0; i < TM; ++i)
#pragma unroll
        for (int j = 0; j < TN; ++j) acc[i][j] = 0.f;

    for (int k0 = 0; k0 < K; k0 += BK) {
        constexpr int A_IT = BM * BK / 4 / 256;
#pragma unroll
        for (int i = 0; i < A_IT; ++i) {
            int idx = t + i * 256;
            int m = idx >> 2, kq = idx & 3;
            float4 v = make_float4(0.f, 0.f, 0.f, 0.f);
            if (m0 + m < M)
                v = *(const float4*)&A[(long)(m0 + m) * K + k0 + kq * 4];
            As[kq * 4 + 0][m] = v.x;
            As[kq * 4 + 1][m] = v.y;
            As[kq * 4 + 2][m] = v.z;
            As[kq * 4 + 3][m] = v.w;
        }
        constexpr int B_IT = BN * BK / 4 / 256;
        if constexpr (B_NK) {
#pragma unroll
            for (int i = 0; i < B_IT; ++i) {
                int idx = t + i * 256;
                int n = idx >> 2, kq = idx & 3;
                float4 v = *(const float4*)&B[(long)(n0 + n) * K + k0 + kq * 4];
                Bs[kq * 4 + 0][n] = v.x;
                Bs[kq * 4 + 1][n] = v.y;
                Bs[kq * 4 + 2][n] = v.z;
                Bs[kq * 4 + 3][n] = v.w;
            }
        } else {
#pragma unroll
            for (int i = 0; i < B_IT; ++i) {
                int idx = t + i * 256;
                int k = idx / (BN / 4), q = idx % (BN / 4);
                float4 v = *(const float4*)&B[(long)(k0 + k) * N + n0 + q * 4];
                *(float4*)&Bs[k][q * 4] = v;
            }
        }
        __syncthreads();
#pragma unroll
        for (int k = 0; k < BK; ++k) {
            float a[TM], bb[TN];
#pragma unroll
            for (int i = 0; i < TM; i += 4) {
                float4 v = *(const float4*)&As[k][ty * TM + i];
                a[i] = v.x; a[i + 1] = v.y; a[i + 2] = v.z; a[i + 3] = v.w;
            }
#pragma unroll
            for (int j = 0; j < TN; j += 4) {
                float4 v = *(const float4*)&Bs[k][tx * TN + j];
                bb[j] = v.x; bb[j + 1] = v.y; bb[j + 2] = v.z; bb[j + 3] = v.w;
            }
#pragma unroll
            for (int i = 0; i < TM; ++i)
#pragma unroll
                for (int j = 0; j < TN; ++j)
                    acc[i][j] = fmaf(a[i], bb[j], acc[i][j]);
        }
        __syncthreads();
    }
    if constexpr (!CT) {
#pragma unroll
        for (int i = 0; i < TM; ++i) {
            int m = m0 + ty * TM + i;
            if (m >= M) continue;
            float bm = SP ? bias[m] : 0.f;
#pragma unroll
            for (int j = 0; j < TN; j += 4) {
                float4 v;
                float* vp = &v.x;
#pragma unroll
                for (int q = 0; q < 4; ++q) {
                    float tv = acc[i][j + q];
                    if constexpr (SP) tv = softplus_f(tv + bm);
                    vp[q] = tv;
                }
                *(float4*)&C[(long)m * N + n0 + tx * TN + j] = v;
            }
        }
    } else {
#pragma unroll
        for (int j = 0; j < TN; ++j) {
            long row = (long)(n0 + tx * TN + j) * M;
#pragma unroll
            for (int iq = 0; iq < TM / 4; ++iq) {
                int m = m0 + ty * TM + iq * 4;
                if (m + 3 >= M) continue;
                float4 v = make_float4(acc[iq * 4 + 0][j], acc[iq * 4 + 1][j],
                                       acc[iq * 4 + 2][j], acc[iq * 4 + 3][j]);
                *(float4*)&C[row + m] = v;
            }
        }
    }
}

// Concat per-direction weights so batched GEMMs can index dir = z>>1.
__global__ __launch_bounds__(256)
void concat_weights(const float* __restrict__ xwf, const float* __restrict__ xwb,
                    const float* __restrict__ dwf, const float* __restrict__ dwb,
                    const float* __restrict__ bf,  const float* __restrict__ bb,
                    float* __restrict__ xwcat, float* __restrict__ dwcat,
                    float* __restrict__ bcat)
{
    int i = blockIdx.x * 256 + threadIdx.x;
    if (i < 196608) { xwcat[i] = xwf[i]; xwcat[196608 + i] = xwb[i]; }
    if (i < 131072) { dwcat[i] = dwf[i]; dwcat[131072 + i] = dwb[i]; }
    if (i < 2048)   { bcat[i]  = bf[i];  bcat[2048 + i]    = bb[i]; }
}

// Depthwise causal conv (k=4) + SiLU, both directions.
// Backward direction computed & stored in reversed-lambda coordinates.
__global__ __launch_bounds__(256)
void conv_silu_kernel(const float* __restrict__ xz,
                      const float* __restrict__ wf, const float* __restrict__ bf,
                      const float* __restrict__ wb, const float* __restrict__ bbk,
                      float* __restrict__ u)
{
    long idx = (long)blockIdx.x * 256 + threadIdx.x;   // (dir,b,d,l)
    int l = (int)(idx & 1023);
    long r = idx >> 10;
    int d = (int)(r & 2047);
    int b = (int)((r >> 11) & 1);
    int dir = (int)(r >> 12);
    const float* x = xz + ((long)b * 4096 + d) * 1024;
    const float* w = dir ? wb : wf;
    float s = dir ? bbk[d] : bf[d];
    if (dir == 0) {
#pragma unroll
        for (int j = 0; j < 4; ++j) {
            int p = l - 3 + j;
            if (p >= 0) s = fmaf(w[d * 4 + j], x[p], s);
        }
    } else {
#pragma unroll
        for (int j = 0; j < 4; ++j) {
            int src = l - 3 + j;
            if (src >= 0) s = fmaf(w[d * 4 + j], x[1023 - src], s);
        }
    }
    u[idx] = s / (1.f + __builtin_amdgcn_exp2f(-s * 1.44269504f));
}

// Fused selective scan. Block = 256 threads = 16 d-groups x 16 n-lanes.
// delta arrives post-softplus. One v_exp per (d,n,l); DPP mirror butterfly:
// quad xor1, quad xor2, row_half_mirror, row_mirror -> full sum in ALL lanes.
__global__ __launch_bounds__(256)
void scan_kernel(const float* __restrict__ u,      // [dirb][2048][1024]
                 const float* __restrict__ delta,  // [dirb][2048][1024]
                 const float* __restrict__ xdbl,   // [dirb][96][1024]
                 const float* __restrict__ Alf, const float* __restrict__ Alb,
                 const float* __restrict__ Df, const float* __restrict__ Db,
                 float* __restrict__ y)            // [dirb][2048][1024]
{
    const int n  = threadIdx.x & 15;
    const int dg = threadIdx.x >> 4;
    const int d0 = blockIdx.x * 16;
    const int b = blockIdx.y, dir = blockIdx.z;
    const int dirb = dir * 2 + b;
    const int d = d0 + dg;
    const float* Alog = dir ? Alb : Alf;
    const float An2 = -expf(Alog[d * 16 + n]) * 1.44269504f;   // -exp(A)*log2(e)
    const float Dd  = (dir ? Db : Df)[d];
    const float* ub = u     + ((long)dirb * 2048 + d0) * 1024;
    const float* db = delta + ((long)dirb * 2048 + d0) * 1024;
    const float* Bb = xdbl  + ((long)dirb * 96 + 64) * 1024;
    const float* Cb = xdbl  + ((long)dirb * 96 + 80) * 1024;
    float* yb = y + ((long)dirb * 2048 + d0) * 1024;

    __shared__ float sD[16][76], sU[16][76], sB[16][76], sC[16][76], sY[16][76];
    float h = 0.f;
    const int dd = threadIdx.x >> 4, q = threadIdx.x & 15;
    for (int l0 = 0; l0 < 1024; l0 += 64) {
        *(float4*)&sD[dd][q * 4] = *(const float4*)&db[dd * 1024 + l0 + q * 4];
        *(float4*)&sU[dd][q * 4] = *(const float4*)&ub[dd * 1024 + l0 + q * 4];
        *(float4*)&sB[dd][q * 4] = *(const float4*)&Bb[dd * 1024 + l0 + q * 4];
        *(float4*)&sC[dd][q * 4] = *(const float4*)&Cb[dd * 1024 + l0 + q * 4];
        __syncthreads();
#pragma unroll 2
        for (int lq = 0; lq < 64; lq += 4) {
            float4 vD = *(const float4*)&sD[dg][lq];
            float4 vU = *(const float4*)&sU[dg][lq];
            float4 vB = *(const float4*)&sB[n][lq];
            float4 vC = *(const float4*)&sC[n][lq];
            float dls[4] = {vD.x, vD.y, vD.z, vD.w};
            float uus[4] = {vU.x, vU.y, vU.z, vU.w};
            float bbs[4] = {vB.x, vB.y, vB.z, vB.w};
            float ccs[4] = {vC.x, vC.y, vC.z, vC.w};
            float fy[4];
#pragma unroll
            for (int k = 0; k < 4; ++k) {
                float dA = __builtin_amdgcn_exp2f(dls[k] * An2);
                h = fmaf(dA, h, dls[k] * uus[k] * bbs[k]);
                float yc = h * ccs[k];
                yc = dpp_add<0xB1>(yc);    // quad_perm xor1
                yc = dpp_add<0x4E>(yc);    // quad_perm xor2
                yc = dpp_add<0x141>(yc);   // row_half_mirror: + other quad in half
                yc = dpp_add<0x140>(yc);   // row_mirror: + other half -> all lanes
                fy[k] = fmaf(Dd, uus[k], yc);
            }
            if (n == 0)
                *(float4*)&sY[dg][lq] = make_float4(fy[0], fy[1], fy[2], fy[3]);
        }
        __syncthreads();
        *(float4*)&yb[dd * 1024 + l0 + q * 4] = *(const float4*)&sY[dd][q * 4];
        __syncthreads();
    }
}

// G[b,d,l] = silu(z[b,d,l]) * (y_f[b,d,l] + y_b[b,d,1023-l])
__global__ __launch_bounds__(256)
void combine_kernel(const float* __restrict__ xz, const float* __restrict__ y,
                    float* __restrict__ G)
{
    long idx = (long)blockIdx.x * 256 + threadIdx.x;   // (b,d,l)
    int l = (int)(idx & 1023);
    long r = idx >> 10;
    int d = (int)(r & 2047);
    int b = (int)(r >> 11);
    float z  = xz[((long)b * 4096 + 2048 + d) * 1024 + l];
    float yf = y[((long)(0 * 2 + b) * 2048 + d) * 1024 + l];
    float yv = y[((long)(1 * 2 + b) * 2048 + d) * 1024 + (1023 - l)];
    float sz = z / (1.f + __builtin_amdgcn_exp2f(-z * 1.44269504f));
    G[idx] = sz * (yf + yv);
}

extern "C" void kernel_launch(void* const* d_in, const int* in_sizes, int n_in,
                              void* d_out, int out_size, void* d_ws, size_t ws_size,
                              hipStream_t stream)
{
    const float* hidden   = (const float*)d_in[0];
    const float* inproj_w = (const float*)d_in[1];
    const float* conv_w   = (const float*)d_in[2];
    const float* conv_b   = (const float*)d_in[3];
    const float* xproj_w  = (const float*)d_in[4];
    const float* dtproj_w = (const float*)d_in[5];
    const float* dt_bias  = (const float*)d_in[6];
    const float* A_log    = (const float*)d_in[7];
    const float* D_skip   = (const float*)d_in[8];
    const float* convb_w  = (const float*)d_in[9];
    const float* convb_b  = (const float*)d_in[10];
    const float* xprojb_w = (const float*)d_in[11];
    const float* dtprojb_w= (const float*)d_in[12];
    const float* dtb_bias = (const float*)d_in[13];
    const float* Ab_log   = (const float*)d_in[14];
    const float* Db_skip  = (const float*)d_in[15];
    const float* outproj_w= (const float*)d_in[16];
    float* out = (float*)d_out;

    float* ws    = (float*)d_ws;
    float* xz    = ws;                      // 8,388,608
    float* u     = ws + 8388608;            // 8,388,608
    float* xdbl  = ws + 16777216;           //   393,216
    float* delta = ws + 17170432;           // 8,388,608
    float* y     = ws + 25559040;           // 8,388,608
    float* G     = delta;                   // alias (delta dead after scan)
    // weight-concat scratch inside y (dead until scan writes y)
    float* xwcat = y;                       // 2*196608
    float* dwcat = y + 393216;              // 2*131072
    float* bcat  = y + 655360;              // 2*2048

    // 0) concat per-dir weights for batched GEMMs
    hipLaunchKernelGGL(concat_weights, dim3(768), dim3(256), 0, stream,
        xproj_w, xprojb_w, dtproj_w, dtprojb_w, dt_bias, dtb_bias,
        xwcat, dwcat, bcat);

    // 1) in_proj: xz[b,e,l] = sum_d W[e,d]*hidden[b,l,d]
    hipLaunchKernelGGL((gemm_f32<128, 128, 8, 8, true, false, false, false>),
        dim3(8, 32, 2), dim3(256), 0, stream,
        inproj_w, hidden, xz, 4096, 1024, 1024,
        0L, (long)1024 * 1024, (long)4096 * 1024, nullptr);

    // 2) conv + silu, both directions
    hipLaunchKernelGGL(conv_silu_kernel, dim3(32768), dim3(256), 0, stream,
        xz, conv_w, conv_b, convb_w, convb_b, u);

    // 3) x_proj batched over dirb: xdbl[k,l] = sum_d W[k,d]*u[d,l]
    hipLaunchKernelGGL((gemm_f32<64, 64, 4, 4, false, false, true, false>),
        dim3(16, 2, 4), dim3(256), 0, stream,
        xwcat, u, xdbl, 96, 1024, 2048,
        196608L, (long)2048 * 1024, (long)96 * 1024, nullptr);

    // 4) dt_proj batched, softplus(.+bias) epilogue
    hipLaunchKernelGGL((gemm_f32<128, 128, 8, 8, false, false, true, true>),
        dim3(8, 16, 4), dim3(256), 0, stream,
        dwcat, xdbl, delta, 2048, 1024, 64,
        131072L, (long)96 * 1024, (long)2048 * 1024, bcat);

    // 5) fused selective scan
    hipLaunchKernelGGL(scan_kernel, dim3(128, 2, 2), dim3(256), 0, stream,
        u, delta, xdbl, A_log, Ab_log, D_skip, Db_skip, y);

    // 6) combine: G = silu(z) * (y_f + reversed y_b)
    hipLaunchKernelGGL(combine_kernel, dim3(16384), dim3(256), 0, stream,
        xz, y, G);

    // 7) out_proj: out[b,l,o] = sum_d W[o,d]*G[b,d,l]  (transposed float4 store)
    hipLaunchKernelGGL((gemm_f32<64, 128, 4, 8, false, true, false, false>),
        dim3(8, 16, 2), dim3(256), 0, stream,
        outproj_w, G, out, 1024, 1024, 2048,
        0L, (long)2048 * 1024, (long)1024 * 1024, nullptr);
}

// Round 7
// 314.940 us; speedup vs baseline: 4.5156x; 2.0639x over previous
//
#include <hip/hip_runtime.h>
#include <math.h>

// ---------------------------------------------------------------------------
// Bidirectional Mamba block, MI355X. Round 6:
//  - in_proj & out_proj -> fp16 MFMA (v_mfma_f32_16x16x32_f16), NT layout,
//    global_load_lds(16B) staging with XOR-swizzled LDS (both-sides),
//    transposed f32x4 C-store.
//  - combine now writes G transposed (fp16 GT[b,l,d]) via LDS tile.
//  - f32->fp16 conversion kernels aliased into dead ws regions (no growth).
//  - scan / conv / x_proj / dt_proj unchanged from round-5 (verified).
// ws layout (f32 elements):
//   xz    [b][4096][1024]           8,388,608
//   u     [dirb][2048][1024]        8,388,608  (head reused: H16 4MB, Win16 8MB
//                                               before conv overwrites u)
//   xdbl  [dirb][96][1024]            393,216
//   delta [dirb][2048][1024]        8,388,608  (head reused as GT fp16 after scan)
//   y     [dirb][2048][1024]        8,388,608  (head: concat scratch early,
//                                               Wout16 after combine)
// ---------------------------------------------------------------------------

typedef _Float16 f16x8 __attribute__((ext_vector_type(8)));
typedef _Float16 f16x4 __attribute__((ext_vector_type(4)));
typedef float    f32x4 __attribute__((ext_vector_type(4)));

__device__ __forceinline__ void gload_lds16(const void* g, void* l) {
    __builtin_amdgcn_global_load_lds(
        (const __attribute__((address_space(1))) void*)g,
        (__attribute__((address_space(3))) void*)l, 16, 0, 0);
}

__device__ __forceinline__ float softplus_f(float x) {
    float e = __builtin_amdgcn_exp2f(-fabsf(x) * 1.44269504f);
    return fmaxf(x, 0.f) + __builtin_amdgcn_logf(1.f + e) * 0.69314718f;
}

template<int CTRL>
__device__ __forceinline__ float dpp_add(float x) {
    int s = __builtin_amdgcn_update_dpp(0, __builtin_bit_cast(int, x),
                                        CTRL, 0xF, 0xF, true);
    return x + __builtin_bit_cast(float, s);
}

// ---------------------------------------------------------------------------
// fp16 NT MFMA GEMM: A MxK (K-contig), B NxK (K-contig), C[n*ldc + m] f32.
// BM = WMW*FM*16, BN = WNW*FN*16, BK = 64. 256 threads = 4 waves.
// LDS: linear rows of 64 fp16 (128B); global source pre-swizzled with
// k_elem ^= (row&7)*8 so swizzled ds_read is bank-spread (rule #21).
// ---------------------------------------------------------------------------
template<int WMW, int WNW, int FM, int FN>
__global__ __launch_bounds__(256)
void gemm_nt_f16(const _Float16* __restrict__ A, const _Float16* __restrict__ B,
                 float* __restrict__ C, int K, int ldc, long sA, long sC)
{
    constexpr int BM = WMW * FM * 16, BN = WNW * FN * 16;
    constexpr int ACH = BM / 8, NCH = (BM + BN) / 8;   // 1024B chunks per K-step
    __shared__ __align__(16) _Float16 lds[(BM + BN) * 64];
    A += (long)blockIdx.z * sA;
    C += (long)blockIdx.z * sC;
    const int m0 = blockIdx.y * BM, n0 = blockIdx.x * BN;
    const int t = threadIdx.x, wid = t >> 6, lane = t & 63;
    const int wm = wid / WNW, wn = wid % WNW;
    const int srow = lane >> 3;                      // row within 8-row chunk
    const int skk  = ((lane & 7) ^ srow) * 8;        // pre-swizzled k element

    f32x4 acc[FM][FN];
#pragma unroll
    for (int i = 0; i < FM; ++i)
#pragma unroll
        for (int j = 0; j < FN; ++j) acc[i][j] = (f32x4){0.f, 0.f, 0.f, 0.f};

    for (int k0 = 0; k0 < K; k0 += 64) {
#pragma unroll
        for (int c = wid; c < NCH; c += 4) {
            const _Float16* gp = (c < ACH)
                ? A + (long)(m0 + c * 8 + srow) * K + k0 + skk
                : B + (long)(n0 + (c - ACH) * 8 + srow) * K + k0 + skk;
            gload_lds16(gp, lds + c * 512);          // wave-uniform LDS base
        }
        __syncthreads();
#pragma unroll
        for (int kw = 0; kw < 2; ++kw) {
            f16x8 af[FM], bf[FN];
#pragma unroll
            for (int i = 0; i < FM; ++i) {
                int r = wm * FM * 16 + i * 16 + (lane & 15);
                af[i] = *(const f16x8*)(lds + r * 64 +
                        (((kw * 4 + (lane >> 4)) ^ (r & 7)) * 8));
            }
#pragma unroll
            for (int j = 0; j < FN; ++j) {
                int r = wn * FN * 16 + j * 16 + (lane & 15);
                bf[j] = *(const f16x8*)(lds + BM * 64 + r * 64 +
                        (((kw * 4 + (lane >> 4)) ^ (r & 7)) * 8));
            }
#pragma unroll
            for (int i = 0; i < FM; ++i)
#pragma unroll
                for (int j = 0; j < FN; ++j)
                    acc[i][j] = __builtin_amdgcn_mfma_f32_16x16x32_f16(
                        af[i], bf[j], acc[i][j], 0, 0, 0);
        }
        __syncthreads();
    }
#pragma unroll
    for (int i = 0; i < FM; ++i)
#pragma unroll
        for (int j = 0; j < FN; ++j) {
            int n = n0 + wn * FN * 16 + j * 16 + (lane & 15);
            int m = m0 + wm * FM * 16 + i * 16 + (lane >> 4) * 4;
            *(f32x4*)&C[(long)n * ldc + m] = acc[i][j];
        }
}

// f32 -> fp16 elementwise
__global__ __launch_bounds__(256)
void cvt_f16_kernel(const float* __restrict__ in, _Float16* __restrict__ out, int n)
{
    int i = (blockIdx.x * 256 + threadIdx.x) * 4;
    if (i + 3 < n) {
        float4 v = *(const float4*)(in + i);
        f16x4 h = {(_Float16)v.x, (_Float16)v.y, (_Float16)v.z, (_Float16)v.w};
        *(f16x4*)(out + i) = h;
    }
}

// ---------------------------------------------------------------------------
// f32 tiled GEMM (kept for x_proj / dt_proj).
// ---------------------------------------------------------------------------
template<int BM, int BN, int TM, int TN, bool AHALF, bool SP>
__global__ __launch_bounds__(256)
void gemm_f32(const float* __restrict__ A, const float* __restrict__ B,
              float* __restrict__ C, int M, int N, int K,
              long sA, long sB, long sC, const float* __restrict__ bias)
{
    constexpr int BK = 16;
    __shared__ float As[BK][BM + 4];
    __shared__ float Bs[BK][BN + 4];
    A += (AHALF ? (long)(blockIdx.z >> 1) : (long)blockIdx.z) * sA;
    B += (long)blockIdx.z * sB;
    C += (long)blockIdx.z * sC;
    if constexpr (SP) bias += (long)(blockIdx.z >> 1) * M;
    const int m0 = blockIdx.y * BM;
    const int n0 = blockIdx.x * BN;
    const int t  = threadIdx.x;
    const int tx = t % (BN / TN);
    const int ty = t / (BN / TN);
    float acc[TM][TN];
#pragma unroll
    for (int i = 0; i < TM; ++i)
#pragma unroll
        for (int j = 0; j < TN; ++j) acc[i][j] = 0.f;

    for (int k0 = 0; k0 < K; k0 += BK) {
        constexpr int A_IT = BM * BK / 4 / 256;
#pragma unroll
        for (int i = 0; i < A_IT; ++i) {
            int idx = t + i * 256;
            int m = idx >> 2, kq = idx & 3;
            float4 v = make_float4(0.f, 0.f, 0.f, 0.f);
            if (m0 + m < M)
                v = *(const float4*)&A[(long)(m0 + m) * K + k0 + kq * 4];
            As[kq * 4 + 0][m] = v.x;
            As[kq * 4 + 1][m] = v.y;
            As[kq * 4 + 2][m] = v.z;
            As[kq * 4 + 3][m] = v.w;
        }
        constexpr int B_IT = BN * BK / 4 / 256;
#pragma unroll
        for (int i = 0; i < B_IT; ++i) {
            int idx = t + i * 256;
            int k = idx / (BN / 4), q = idx % (BN / 4);
            float4 v = *(const float4*)&B[(long)(k0 + k) * N + n0 + q * 4];
            *(float4*)&Bs[k][q * 4] = v;
        }
        __syncthreads();
#pragma unroll
        for (int k = 0; k < BK; ++k) {
            float a[TM], bb[TN];
#pragma unroll
            for (int i = 0; i < TM; i += 4) {
                float4 v = *(const float4*)&As[k][ty * TM + i];
                a[i] = v.x; a[i + 1] = v.y; a[i + 2] = v.z; a[i + 3] = v.w;
            }
#pragma unroll
            for (int j = 0; j < TN; j += 4) {
                float4 v = *(const float4*)&Bs[k][tx * TN + j];
                bb[j] = v.x; bb[j + 1] = v.y; bb[j + 2] = v.z; bb[j + 3] = v.w;
            }
#pragma unroll
            for (int i = 0; i < TM; ++i)
#pragma unroll
                for (int j = 0; j < TN; ++j)
                    acc[i][j] = fmaf(a[i], bb[j], acc[i][j]);
        }
        __syncthreads();
    }
#pragma unroll
    for (int i = 0; i < TM; ++i) {
        int m = m0 + ty * TM + i;
        if (m >= M) continue;
        float bm = SP ? bias[m] : 0.f;
#pragma unroll
        for (int j = 0; j < TN; j += 4) {
            float4 v;
            float* vp = &v.x;
#pragma unroll
            for (int q = 0; q < 4; ++q) {
                float tv = acc[i][j + q];
                if constexpr (SP) tv = softplus_f(tv + bm);
                vp[q] = tv;
            }
            *(float4*)&C[(long)m * N + n0 + tx * TN + j] = v;
        }
    }
}

// Concat per-direction weights so batched GEMMs can index dir = z>>1.
__global__ __launch_bounds__(256)
void concat_weights(const float* __restrict__ xwf, const float* __restrict__ xwb,
                    const float* __restrict__ dwf, const float* __restrict__ dwb,
                    const float* __restrict__ bf,  const float* __restrict__ bb,
                    float* __restrict__ xwcat, float* __restrict__ dwcat,
                    float* __restrict__ bcat)
{
    int i = blockIdx.x * 256 + threadIdx.x;
    if (i < 196608) { xwcat[i] = xwf[i]; xwcat[196608 + i] = xwb[i]; }
    if (i < 131072) { dwcat[i] = dwf[i]; dwcat[131072 + i] = dwb[i]; }
    if (i < 2048)   { bcat[i]  = bf[i];  bcat[2048 + i]    = bb[i]; }
}

// Depthwise causal conv (k=4) + SiLU, both directions (bwd in reversed coords).
__global__ __launch_bounds__(256)
void conv_silu_kernel(const float* __restrict__ xz,
                      const float* __restrict__ wf, const float* __restrict__ bf,
                      const float* __restrict__ wb, const float* __restrict__ bbk,
                      float* __restrict__ u)
{
    long idx = (long)blockIdx.x * 256 + threadIdx.x;   // (dir,b,d,l)
    int l = (int)(idx & 1023);
    long r = idx >> 10;
    int d = (int)(r & 2047);
    int b = (int)((r >> 11) & 1);
    int dir = (int)(r >> 12);
    const float* x = xz + ((long)b * 4096 + d) * 1024;
    const float* w = dir ? wb : wf;
    float s = dir ? bbk[d] : bf[d];
    if (dir == 0) {
#pragma unroll
        for (int j = 0; j < 4; ++j) {
            int p = l - 3 + j;
            if (p >= 0) s = fmaf(w[d * 4 + j], x[p], s);
        }
    } else {
#pragma unroll
        for (int j = 0; j < 4; ++j) {
            int src = l - 3 + j;
            if (src >= 0) s = fmaf(w[d * 4 + j], x[1023 - src], s);
        }
    }
    u[idx] = s / (1.f + __builtin_amdgcn_exp2f(-s * 1.44269504f));
}

// Fused selective scan (verified round-6): DPP mirror butterfly reduce.
__global__ __launch_bounds__(256)
void scan_kernel(const float* __restrict__ u, const float* __restrict__ delta,
                 const float* __restrict__ xdbl,
                 const float* __restrict__ Alf, const float* __restrict__ Alb,
                 const float* __restrict__ Df, const float* __restrict__ Db,
                 float* __restrict__ y)
{
    const int n  = threadIdx.x & 15;
    const int dg = threadIdx.x >> 4;
    const int d0 = blockIdx.x * 16;
    const int b = blockIdx.y, dir = blockIdx.z;
    const int dirb = dir * 2 + b;
    const int d = d0 + dg;
    const float* Alog = dir ? Alb : Alf;
    const float An2 = -expf(Alog[d * 16 + n]) * 1.44269504f;
    const float Dd  = (dir ? Db : Df)[d];
    const float* ub = u     + ((long)dirb * 2048 + d0) * 1024;
    const float* db = delta + ((long)dirb * 2048 + d0) * 1024;
    const float* Bb = xdbl  + ((long)dirb * 96 + 64) * 1024;
    const float* Cb = xdbl  + ((long)dirb * 96 + 80) * 1024;
    float* yb = y + ((long)dirb * 2048 + d0) * 1024;

    __shared__ float sD[16][76], sU[16][76], sB[16][76], sC[16][76], sY[16][76];
    float h = 0.f;
    const int dd = threadIdx.x >> 4, q = threadIdx.x & 15;
    for (int l0 = 0; l0 < 1024; l0 += 64) {
        *(float4*)&sD[dd][q * 4] = *(const float4*)&db[dd * 1024 + l0 + q * 4];
        *(float4*)&sU[dd][q * 4] = *(const float4*)&ub[dd * 1024 + l0 + q * 4];
        *(float4*)&sB[dd][q * 4] = *(const float4*)&Bb[dd * 1024 + l0 + q * 4];
        *(float4*)&sC[dd][q * 4] = *(const float4*)&Cb[dd * 1024 + l0 + q * 4];
        __syncthreads();
#pragma unroll 2
        for (int lq = 0; lq < 64; lq += 4) {
            float4 vD = *(const float4*)&sD[dg][lq];
            float4 vU = *(const float4*)&sU[dg][lq];
            float4 vB = *(const float4*)&sB[n][lq];
            float4 vC = *(const float4*)&sC[n][lq];
            float dls[4] = {vD.x, vD.y, vD.z, vD.w};
            float uus[4] = {vU.x, vU.y, vU.z, vU.w};
            float bbs[4] = {vB.x, vB.y, vB.z, vB.w};
            float ccs[4] = {vC.x, vC.y, vC.z, vC.w};
            float fy[4];
#pragma unroll
            for (int k = 0; k < 4; ++k) {
                float dA = __builtin_amdgcn_exp2f(dls[k] * An2);
                h = fmaf(dA, h, dls[k] * uus[k] * bbs[k]);
                float yc = h * ccs[k];
                yc = dpp_add<0xB1>(yc);    // quad_perm xor1
                yc = dpp_add<0x4E>(yc);    // quad_perm xor2
                yc = dpp_add<0x141>(yc);   // row_half_mirror
                yc = dpp_add<0x140>(yc);   // row_mirror -> full sum, all lanes
                fy[k] = fmaf(Dd, uus[k], yc);
            }
            if (n == 0)
                *(float4*)&sY[dg][lq] = make_float4(fy[0], fy[1], fy[2], fy[3]);
        }
        __syncthreads();
        *(float4*)&yb[dd * 1024 + l0 + q * 4] = *(const float4*)&sY[dd][q * 4];
        __syncthreads();
    }
}

// G = silu(z) * (y_f + rev y_b), written TRANSPOSED as fp16 GT[b][l][d].
__global__ __launch_bounds__(256)
void combine_T_kernel(const float* __restrict__ xz, const float* __restrict__ y,
                      _Float16* __restrict__ GT)
{
    __shared__ float Ls[64][65];
    const int d0 = blockIdx.x * 64, l0 = blockIdx.y * 64, b = blockIdx.z;
    const int t = threadIdx.x;
#pragma unroll
    for (int rep = 0; rep < 4; ++rep) {
        int i = rep * 256 + t;
        int dl = i >> 4;
        int lq = (i & 15) * 4;
        const float* zp  = xz + ((long)b * 4096 + 2048 + d0 + dl) * 1024 + l0 + lq;
        const float* yfp = y  + ((long)(b)     * 2048 + d0 + dl) * 1024 + l0 + lq;
        const float* ybp = y  + ((long)(2 + b) * 2048 + d0 + dl) * 1024 + (1020 - l0 - lq);
        float4 vz = *(const float4*)zp;
        float4 vf = *(const float4*)yfp;
        float4 vb = *(const float4*)ybp;
        float zz[4]  = {vz.x, vz.y, vz.z, vz.w};
        float ff[4]  = {vf.x, vf.y, vf.z, vf.w};
        float bbv[4] = {vb.w, vb.z, vb.y, vb.x};   // reversed
#pragma unroll
        for (int qq = 0; qq < 4; ++qq) {
            float z = zz[qq];
            float sz = z / (1.f + __builtin_amdgcn_exp2f(-z * 1.44269504f));
            Ls[dl][lq + qq] = sz * (ff[qq] + bbv[qq]);
        }
    }
    __syncthreads();
#pragma unroll
    for (int rep = 0; rep < 4; ++rep) {
        int i = rep * 256 + t;
        int ll = i >> 4;
        int dq = (i & 15) * 4;
        f16x4 h = {(_Float16)Ls[dq][ll], (_Float16)Ls[dq + 1][ll],
                   (_Float16)Ls[dq + 2][ll], (_Float16)Ls[dq + 3][ll]};
        *(f16x4*)(GT + ((long)(b * 1024 + l0 + ll)) * 2048 + d0 + dq) = h;
    }
}

extern "C" void kernel_launch(void* const* d_in, const int* in_sizes, int n_in,
                              void* d_out, int out_size, void* d_ws, size_t ws_size,
                              hipStream_t stream)
{
    const float* hidden   = (const float*)d_in[0];
    const float* inproj_w = (const float*)d_in[1];
    const float* conv_w   = (const float*)d_in[2];
    const float* conv_b   = (const float*)d_in[3];
    const float* xproj_w  = (const float*)d_in[4];
    const float* dtproj_w = (const float*)d_in[5];
    const float* dt_bias  = (const float*)d_in[6];
    const float* A_log    = (const float*)d_in[7];
    const float* D_skip   = (const float*)d_in[8];
    const float* convb_w  = (const float*)d_in[9];
    const float* convb_b  = (const float*)d_in[10];
    const float* xprojb_w = (const float*)d_in[11];
    const float* dtprojb_w= (const float*)d_in[12];
    const float* dtb_bias = (const float*)d_in[13];
    const float* Ab_log   = (const float*)d_in[14];
    const float* Db_skip  = (const float*)d_in[15];
    const float* outproj_w= (const float*)d_in[16];
    float* out = (float*)d_out;

    float* ws    = (float*)d_ws;
    float* xz    = ws;
    float* u     = ws + 8388608;
    float* xdbl  = ws + 16777216;
    float* delta = ws + 17170432;
    float* y     = ws + 25559040;
    // fp16 aliases in temporally-dead regions:
    _Float16* H16    = (_Float16*)u;                 // 4 MB, dead before conv
    _Float16* Win16  = (_Float16*)(u + 1048576);     // 8 MB, dead before conv
    _Float16* GT     = (_Float16*)delta;             // 8 MB, after scan
    _Float16* Wout16 = (_Float16*)y;                 // 4 MB, after combine
    // concat scratch in y head (dead until scan writes y)
    float* xwcat = y;
    float* dwcat = y + 393216;
    float* bcat  = y + 655360;

    // 0) f32 -> fp16 conversions (into dead u-region head)
    hipLaunchKernelGGL(cvt_f16_kernel, dim3(2048), dim3(256), 0, stream,
        hidden, H16, 2097152);
    hipLaunchKernelGGL(cvt_f16_kernel, dim3(4096), dim3(256), 0, stream,
        inproj_w, Win16, 4194304);

    // 0b) concat per-dir weights for batched f32 GEMMs
    hipLaunchKernelGGL(concat_weights, dim3(768), dim3(256), 0, stream,
        xproj_w, xprojb_w, dtproj_w, dtprojb_w, dt_bias, dtb_bias,
        xwcat, dwcat, bcat);

    // 1) in_proj MFMA: C[e,l] per batch; A=H16 (l rows), B=Win16 (e rows)
    hipLaunchKernelGGL((gemm_nt_f16<2, 2, 4, 4>),
        dim3(32, 8, 2), dim3(256), 0, stream,
        H16, Win16, xz, 1024, 1024, 1048576L, 4194304L);

    // 2) conv + silu (overwrites u region incl. H16/Win16 — after in_proj)
    hipLaunchKernelGGL(conv_silu_kernel, dim3(32768), dim3(256), 0, stream,
        xz, conv_w, conv_b, convb_w, convb_b, u);

    // 3) x_proj batched over dirb
    hipLaunchKernelGGL((gemm_f32<64, 64, 4, 4, true, false>),
        dim3(16, 2, 4), dim3(256), 0, stream,
        xwcat, u, xdbl, 96, 1024, 2048,
        196608L, (long)2048 * 1024, (long)96 * 1024, nullptr);

    // 4) dt_proj batched, softplus(.+bias) epilogue
    hipLaunchKernelGGL((gemm_f32<128, 128, 8, 8, true, true>),
        dim3(8, 16, 4), dim3(256), 0, stream,
        dwcat, xdbl, delta, 2048, 1024, 64,
        131072L, (long)96 * 1024, (long)2048 * 1024, bcat);

    // 5) fused selective scan
    hipLaunchKernelGGL(scan_kernel, dim3(128, 2, 2), dim3(256), 0, stream,
        u, delta, xdbl, A_log, Ab_log, D_skip, Db_skip, y);

    // 6) combine -> GT fp16 [b][l][d] (reads all of y & z-half of xz)
    hipLaunchKernelGGL(combine_T_kernel, dim3(32, 16, 2), dim3(256), 0, stream,
        xz, y, GT);

    // 7) W_out -> fp16 (into y head, after combine consumed y)
    hipLaunchKernelGGL(cvt_f16_kernel, dim3(2048), dim3(256), 0, stream,
        outproj_w, Wout16, 2097152);

    // 8) out_proj MFMA: out[(b,l)][o]; A=Wout16 (o rows), B=GT ((b,l) rows)
    hipLaunchKernelGGL((gemm_nt_f16<4, 1, 2, 4>),
        dim3(32, 8, 1), dim3(256), 0, stream,
        Wout16, GT, out, 2048, 1024, 0L, 0L);
}

// Round 8
// 223.137 us; speedup vs baseline: 6.3734x; 1.4114x over previous
//
#include <hip/hip_runtime.h>
#include <math.h>

// ---------------------------------------------------------------------------
// Bidirectional Mamba block, MI355X. Round 8:
//  - x_proj -> fp16 MFMA split-K=8: A = u^T staged in-kernel (f32 read,
//    cvt fp16, XOR-swizzled LDS transpose), B = xw fp16 via global_load_lds,
//    partials in dead delta region + deterministic reduce. 118us -> ~15us.
//  - concat_weights also emits xw fp16; f32 xwcat dropped.
//  - in/out_proj MFMA, conv, dt_proj, scan, combine unchanged (verified r7).
// ws layout (f32 elements):
//   xz    [b][4096][1024]           8,388,608
//   u     [dirb][2048][1024]        8,388,608  (head: H16/Win16 before conv)
//   xdbl  [dirb][96][1024]            393,216
//   delta [dirb][2048][1024]        8,388,608  (head: x_proj partials before
//                                               dt_proj; GT fp16 after scan)
//   y     [dirb][2048][1024]        8,388,608  (head: dwcat/bcat/xw16 scratch,
//                                               Wout16 after combine)
// ---------------------------------------------------------------------------

typedef _Float16 f16x8 __attribute__((ext_vector_type(8)));
typedef _Float16 f16x4 __attribute__((ext_vector_type(4)));
typedef float    f32x4 __attribute__((ext_vector_type(4)));

__device__ __forceinline__ void gload_lds16(const void* g, void* l) {
    __builtin_amdgcn_global_load_lds(
        (const __attribute__((address_space(1))) void*)g,
        (__attribute__((address_space(3))) void*)l, 16, 0, 0);
}

__device__ __forceinline__ float softplus_f(float x) {
    float e = __builtin_amdgcn_exp2f(-fabsf(x) * 1.44269504f);
    return fmaxf(x, 0.f) + __builtin_amdgcn_logf(1.f + e) * 0.69314718f;
}

template<int CTRL>
__device__ __forceinline__ float dpp_add(float x) {
    int s = __builtin_amdgcn_update_dpp(0, __builtin_bit_cast(int, x),
                                        CTRL, 0xF, 0xF, true);
    return x + __builtin_bit_cast(float, s);
}

// ---------------------------------------------------------------------------
// fp16 NT MFMA GEMM (in_proj / out_proj): A MxK, B NxK (both K-contig),
// C[n*ldc+m] f32. global_load_lds staging, pre-swizzled source (rule #21).
// ---------------------------------------------------------------------------
template<int WMW, int WNW, int FM, int FN>
__global__ __launch_bounds__(256)
void gemm_nt_f16(const _Float16* __restrict__ A, const _Float16* __restrict__ B,
                 float* __restrict__ C, int K, int ldc, long sA, long sC)
{
    constexpr int BM = WMW * FM * 16, BN = WNW * FN * 16;
    constexpr int ACH = BM / 8, NCH = (BM + BN) / 8;
    __shared__ __align__(16) _Float16 lds[(BM + BN) * 64];
    A += (long)blockIdx.z * sA;
    C += (long)blockIdx.z * sC;
    const int m0 = blockIdx.y * BM, n0 = blockIdx.x * BN;
    const int t = threadIdx.x, wid = t >> 6, lane = t & 63;
    const int wm = wid / WNW, wn = wid % WNW;
    const int srow = lane >> 3;
    const int skk  = ((lane & 7) ^ srow) * 8;

    f32x4 acc[FM][FN];
#pragma unroll
    for (int i = 0; i < FM; ++i)
#pragma unroll
        for (int j = 0; j < FN; ++j) acc[i][j] = (f32x4){0.f, 0.f, 0.f, 0.f};

    for (int k0 = 0; k0 < K; k0 += 64) {
#pragma unroll
        for (int c = wid; c < NCH; c += 4) {
            const _Float16* gp = (c < ACH)
                ? A + (long)(m0 + c * 8 + srow) * K + k0 + skk
                : B + (long)(n0 + (c - ACH) * 8 + srow) * K + k0 + skk;
            gload_lds16(gp, lds + c * 512);
        }
        __syncthreads();
#pragma unroll
        for (int kw = 0; kw < 2; ++kw) {
            f16x8 af[FM], bf[FN];
#pragma unroll
            for (int i = 0; i < FM; ++i) {
                int r = wm * FM * 16 + i * 16 + (lane & 15);
                af[i] = *(const f16x8*)(lds + r * 64 +
                        (((kw * 4 + (lane >> 4)) ^ (r & 7)) * 8));
            }
#pragma unroll
            for (int j = 0; j < FN; ++j) {
                int r = wn * FN * 16 + j * 16 + (lane & 15);
                bf[j] = *(const f16x8*)(lds + BM * 64 + r * 64 +
                        (((kw * 4 + (lane >> 4)) ^ (r & 7)) * 8));
            }
#pragma unroll
            for (int i = 0; i < FM; ++i)
#pragma unroll
                for (int j = 0; j < FN; ++j)
                    acc[i][j] = __builtin_amdgcn_mfma_f32_16x16x32_f16(
                        af[i], bf[j], acc[i][j], 0, 0, 0);
        }
        __syncthreads();
    }
#pragma unroll
    for (int i = 0; i < FM; ++i)
#pragma unroll
        for (int j = 0; j < FN; ++j) {
            int n = n0 + wn * FN * 16 + j * 16 + (lane & 15);
            int m = m0 + wm * FM * 16 + i * 16 + (lane >> 4) * 4;
            *(f32x4*)&C[(long)n * ldc + m] = acc[i][j];
        }
}

// ---------------------------------------------------------------------------
// x_proj fp16 MFMA, split-K. A = u^T (M=1024 l-rows), staged in-kernel from
// f32 u[d][l] with transpose+cvt into XOR-swizzled LDS. B = xw16 (N=96 rows,
// K-contig) via global_load_lds. C[n*1024+m] partials, one per split.
// BM=128, BN=96, BK=64; WMW=2, WNW=2, FM=4, FN=3. grid (8, SK, 4dirb).
// ---------------------------------------------------------------------------
#define XP_SK 8
__global__ __launch_bounds__(256)
void xproj_f16_kernel(const float* __restrict__ u, const _Float16* __restrict__ xw16,
                      float* __restrict__ pb)
{
    __shared__ __align__(16) _Float16 Asw[128 * 64];
    __shared__ __align__(16) _Float16 Bsw[96 * 64];
    const int t = threadIdx.x, wid = t >> 6, lane = t & 63;
    const int wm = wid >> 1, wn = wid & 1;
    const int m0 = blockIdx.x * 128;
    const int sk = blockIdx.y, dirb = blockIdx.z;
    const float* ub = u + (long)dirb * 2048 * 1024;
    const _Float16* Bw = xw16 + (long)(dirb >> 1) * 96 * 2048;
    const int srow = lane >> 3;
    const int skk  = ((lane & 7) ^ srow) * 8;
    const int lloc = (t & 31) * 4;        // A-staging: l within tile
    const int kslt = t >> 5;              // A-staging: k-octet 0..7

    f32x4 acc[4][3];
#pragma unroll
    for (int i = 0; i < 4; ++i)
#pragma unroll
        for (int j = 0; j < 3; ++j) acc[i][j] = (f32x4){0.f, 0.f, 0.f, 0.f};

    for (int ks = 0; ks < 2048 / XP_SK; ks += 64) {
        const int k0 = sk * (2048 / XP_SK) + ks;
        // B: 12 chunks of 8 rows via global_load_lds (pre-swizzled source)
#pragma unroll
        for (int c = wid; c < 12; c += 4)
            gload_lds16(Bw + (long)(c * 8 + srow) * 2048 + k0 + skk, Bsw + c * 512);
        // A: read 8 f32x4 (8 k x 4 l), cvt, transpose-write 4 x f16x8
        float av[8][4];
#pragma unroll
        for (int kk = 0; kk < 8; ++kk) {
            f32x4 v = *(const f32x4*)&ub[(long)(k0 + kslt * 8 + kk) * 1024 + m0 + lloc];
            av[kk][0] = v.x; av[kk][1] = v.y; av[kk][2] = v.z; av[kk][3] = v.w;
        }
#pragma unroll
        for (int q = 0; q < 4; ++q) {
            int l = lloc + q;
            f16x8 h = {(_Float16)av[0][q], (_Float16)av[1][q], (_Float16)av[2][q],
                       (_Float16)av[3][q], (_Float16)av[4][q], (_Float16)av[5][q],
                       (_Float16)av[6][q], (_Float16)av[7][q]};
            *(f16x8*)(Asw + l * 64 + ((kslt ^ (l & 7)) * 8)) = h;
        }
        __syncthreads();
#pragma unroll
        for (int kw = 0; kw < 2; ++kw) {
            f16x8 af[4], bf[3];
#pragma unroll
            for (int i = 0; i < 4; ++i) {
                int r = wm * 64 + i * 16 + (lane & 15);
                af[i] = *(const f16x8*)(Asw + r * 64 +
                        (((kw * 4 + (lane >> 4)) ^ (r & 7)) * 8));
            }
#pragma unroll
            for (int j = 0; j < 3; ++j) {
                int r = wn * 48 + j * 16 + (lane & 15);
                bf[j] = *(const f16x8*)(Bsw + r * 64 +
                        (((kw * 4 + (lane >> 4)) ^ (r & 7)) * 8));
            }
#pragma unroll
            for (int i = 0; i < 4; ++i)
#pragma unroll
                for (int j = 0; j < 3; ++j)
                    acc[i][j] = __builtin_amdgcn_mfma_f32_16x16x32_f16(
                        af[i], bf[j], acc[i][j], 0, 0, 0);
        }
        __syncthreads();
    }
    float* Cp = pb + ((long)sk * 4 + dirb) * 96 * 1024;
#pragma unroll
    for (int i = 0; i < 4; ++i)
#pragma unroll
        for (int j = 0; j < 3; ++j) {
            int n = wn * 48 + j * 16 + (lane & 15);
            int m = m0 + wm * 64 + i * 16 + (lane >> 4) * 4;
            *(f32x4*)&Cp[(long)n * 1024 + m] = acc[i][j];
        }
}

// Sum XP_SK split-K partials -> xdbl
__global__ __launch_bounds__(256)
void xreduce_kernel(const float* __restrict__ pb, float* __restrict__ xdbl)
{
    int f = (blockIdx.x * 256 + threadIdx.x) * 4;   // over 4*96*1024 f32
    f32x4 s = (f32x4){0.f, 0.f, 0.f, 0.f};
#pragma unroll
    for (int sk = 0; sk < XP_SK; ++sk)
        s += *(const f32x4*)(pb + (long)sk * 393216 + f);
    *(f32x4*)(xdbl + f) = s;
}

// f32 -> fp16 elementwise
__global__ __launch_bounds__(256)
void cvt_f16_kernel(const float* __restrict__ in, _Float16* __restrict__ out, int n)
{
    int i = (blockIdx.x * 256 + threadIdx.x) * 4;
    if (i + 3 < n) {
        float4 v = *(const float4*)(in + i);
        f16x4 h = {(_Float16)v.x, (_Float16)v.y, (_Float16)v.z, (_Float16)v.w};
        *(f16x4*)(out + i) = h;
    }
}

// ---------------------------------------------------------------------------
// f32 tiled GEMM (dt_proj only). B is KxN (N-contig).
// ---------------------------------------------------------------------------
template<int BM, int BN, int TM, int TN, bool AHALF, bool SP>
__global__ __launch_bounds__(256)
void gemm_f32(const float* __restrict__ A, const float* __restrict__ B,
              float* __restrict__ C, int M, int N, int K,
              long sA, long sB, long sC, const float* __restrict__ bias)
{
    constexpr int BK = 16;
    __shared__ float As[BK][BM + 4];
    __shared__ float Bs[BK][BN + 4];
    A += (AHALF ? (long)(blockIdx.z >> 1) : (long)blockIdx.z) * sA;
    B += (long)blockIdx.z * sB;
    C += (long)blockIdx.z * sC;
    if constexpr (SP) bias += (long)(blockIdx.z >> 1) * M;
    const int m0 = blockIdx.y * BM;
    const int n0 = blockIdx.x * BN;
    const int t  = threadIdx.x;
    const int tx = t % (BN / TN);
    const int ty = t / (BN / TN);
    float acc[TM][TN];
#pragma unroll
    for (int i = 0; i < TM; ++i)
#pragma unroll
        for (int j = 0; j < TN; ++j) acc[i][j] = 0.f;

    for (int k0 = 0; k0 < K; k0 += BK) {
        constexpr int A_IT = BM * BK / 4 / 256;
#pragma unroll
        for (int i = 0; i < A_IT; ++i) {
            int idx = t + i * 256;
            int m = idx >> 2, kq = idx & 3;
            float4 v = make_float4(0.f, 0.f, 0.f, 0.f);
            if (m0 + m < M)
                v = *(const float4*)&A[(long)(m0 + m) * K + k0 + kq * 4];
            As[kq * 4 + 0][m] = v.x;
            As[kq * 4 + 1][m] = v.y;
            As[kq * 4 + 2][m] = v.z;
            As[kq * 4 + 3][m] = v.w;
        }
        constexpr int B_IT = BN * BK / 4 / 256;
#pragma unroll
        for (int i = 0; i < B_IT; ++i) {
            int idx = t + i * 256;
            int k = idx / (BN / 4), q = idx % (BN / 4);
            float4 v = *(const float4*)&B[(long)(k0 + k) * N + n0 + q * 4];
            *(float4*)&Bs[k][q * 4] = v;
        }
        __syncthreads();
#pragma unroll
        for (int k = 0; k < BK; ++k) {
            float a[TM], bb[TN];
#pragma unroll
            for (int i = 0; i < TM; i += 4) {
                float4 v = *(const float4*)&As[k][ty * TM + i];
                a[i] = v.x; a[i + 1] = v.y; a[i + 2] = v.z; a[i + 3] = v.w;
            }
#pragma unroll
            for (int j = 0; j < TN; j += 4) {
                float4 v = *(const float4*)&Bs[k][tx * TN + j];
                bb[j] = v.x; bb[j + 1] = v.y; bb[j + 2] = v.z; bb[j + 3] = v.w;
            }
#pragma unroll
            for (int i = 0; i < TM; ++i)
#pragma unroll
                for (int j = 0; j < TN; ++j)
                    acc[i][j] = fmaf(a[i], bb[j], acc[i][j]);
        }
        __syncthreads();
    }
#pragma unroll
    for (int i = 0; i < TM; ++i) {
        int m = m0 + ty * TM + i;
        if (m >= M) continue;
        float bm = SP ? bias[m] : 0.f;
#pragma unroll
        for (int j = 0; j < TN; j += 4) {
            float4 v;
            float* vp = &v.x;
#pragma unroll
            for (int q = 0; q < 4; ++q) {
                float tv = acc[i][j + q];
                if constexpr (SP) tv = softplus_f(tv + bm);
                vp[q] = tv;
            }
            *(float4*)&C[(long)m * N + n0 + tx * TN + j] = v;
        }
    }
}

// Concat dt_proj weights (f32) + bias, and emit x_proj weights as fp16.
__global__ __launch_bounds__(256)
void concat_weights(const float* __restrict__ xwf, const float* __restrict__ xwb,
                    const float* __restrict__ dwf, const float* __restrict__ dwb,
                    const float* __restrict__ bf,  const float* __restrict__ bb,
                    _Float16* __restrict__ xw16, float* __restrict__ dwcat,
                    float* __restrict__ bcat)
{
    int i = blockIdx.x * 256 + threadIdx.x;
    if (i < 196608) { xw16[i] = (_Float16)xwf[i]; xw16[196608 + i] = (_Float16)xwb[i]; }
    if (i < 131072) { dwcat[i] = dwf[i]; dwcat[131072 + i] = dwb[i]; }
    if (i < 2048)   { bcat[i]  = bf[i];  bcat[2048 + i]    = bb[i]; }
}

// Depthwise causal conv (k=4) + SiLU, both directions (bwd in reversed coords).
__global__ __launch_bounds__(256)
void conv_silu_kernel(const float* __restrict__ xz,
                      const float* __restrict__ wf, const float* __restrict__ bf,
                      const float* __restrict__ wb, const float* __restrict__ bbk,
                      float* __restrict__ u)
{
    long idx = (long)blockIdx.x * 256 + threadIdx.x;   // (dir,b,d,l)
    int l = (int)(idx & 1023);
    long r = idx >> 10;
    int d = (int)(r & 2047);
    int b = (int)((r >> 11) & 1);
    int dir = (int)(r >> 12);
    const float* x = xz + ((long)b * 4096 + d) * 1024;
    const float* w = dir ? wb : wf;
    float s = dir ? bbk[d] : bf[d];
    if (dir == 0) {
#pragma unroll
        for (int j = 0; j < 4; ++j) {
            int p = l - 3 + j;
            if (p >= 0) s = fmaf(w[d * 4 + j], x[p], s);
        }
    } else {
#pragma unroll
        for (int j = 0; j < 4; ++j) {
            int src = l - 3 + j;
            if (src >= 0) s = fmaf(w[d * 4 + j], x[1023 - src], s);
        }
    }
    u[idx] = s / (1.f + __builtin_amdgcn_exp2f(-s * 1.44269504f));
}

// Fused selective scan (verified): DPP mirror butterfly reduce.
__global__ __launch_bounds__(256)
void scan_kernel(const float* __restrict__ u, const float* __restrict__ delta,
                 const float* __restrict__ xdbl,
                 const float* __restrict__ Alf, const float* __restrict__ Alb,
                 const float* __restrict__ Df, const float* __restrict__ Db,
                 float* __restrict__ y)
{
    const int n  = threadIdx.x & 15;
    const int dg = threadIdx.x >> 4;
    const int d0 = blockIdx.x * 16;
    const int b = blockIdx.y, dir = blockIdx.z;
    const int dirb = dir * 2 + b;
    const int d = d0 + dg;
    const float* Alog = dir ? Alb : Alf;
    const float An2 = -expf(Alog[d * 16 + n]) * 1.44269504f;
    const float Dd  = (dir ? Db : Df)[d];
    const float* ub = u     + ((long)dirb * 2048 + d0) * 1024;
    const float* db = delta + ((long)dirb * 2048 + d0) * 1024;
    const float* Bb = xdbl  + ((long)dirb * 96 + 64) * 1024;
    const float* Cb = xdbl  + ((long)dirb * 96 + 80) * 1024;
    float* yb = y + ((long)dirb * 2048 + d0) * 1024;

    __shared__ float sD[16][76], sU[16][76], sB[16][76], sC[16][76], sY[16][76];
    float h = 0.f;
    const int dd = threadIdx.x >> 4, q = threadIdx.x & 15;
    for (int l0 = 0; l0 < 1024; l0 += 64) {
        *(float4*)&sD[dd][q * 4] = *(const float4*)&db[dd * 1024 + l0 + q * 4];
        *(float4*)&sU[dd][q * 4] = *(const float4*)&ub[dd * 1024 + l0 + q * 4];
        *(float4*)&sB[dd][q * 4] = *(const float4*)&Bb[dd * 1024 + l0 + q * 4];
        *(float4*)&sC[dd][q * 4] = *(const float4*)&Cb[dd * 1024 + l0 + q * 4];
        __syncthreads();
#pragma unroll 2
        for (int lq = 0; lq < 64; lq += 4) {
            float4 vD = *(const float4*)&sD[dg][lq];
            float4 vU = *(const float4*)&sU[dg][lq];
            float4 vB = *(const float4*)&sB[n][lq];
            float4 vC = *(const float4*)&sC[n][lq];
            float dls[4] = {vD.x, vD.y, vD.z, vD.w};
            float uus[4] = {vU.x, vU.y, vU.z, vU.w};
            float bbs[4] = {vB.x, vB.y, vB.z, vB.w};
            float ccs[4] = {vC.x, vC.y, vC.z, vC.w};
            float fy[4];
#pragma unroll
            for (int k = 0; k < 4; ++k) {
                float dA = __builtin_amdgcn_exp2f(dls[k] * An2);
                h = fmaf(dA, h, dls[k] * uus[k] * bbs[k]);
                float yc = h * ccs[k];
                yc = dpp_add<0xB1>(yc);    // quad_perm xor1
                yc = dpp_add<0x4E>(yc);    // quad_perm xor2
                yc = dpp_add<0x141>(yc);   // row_half_mirror
                yc = dpp_add<0x140>(yc);   // row_mirror -> full sum, all lanes
                fy[k] = fmaf(Dd, uus[k], yc);
            }
            if (n == 0)
                *(float4*)&sY[dg][lq] = make_float4(fy[0], fy[1], fy[2], fy[3]);
        }
        __syncthreads();
        *(float4*)&yb[dd * 1024 + l0 + q * 4] = *(const float4*)&sY[dd][q * 4];
        __syncthreads();
    }
}

// G = silu(z) * (y_f + rev y_b), written TRANSPOSED as fp16 GT[b][l][d].
__global__ __launch_bounds__(256)
void combine_T_kernel(const float* __restrict__ xz, const float* __restrict__ y,
                      _Float16* __restrict__ GT)
{
    __shared__ float Ls[64][65];
    const int d0 = blockIdx.x * 64, l0 = blockIdx.y * 64, b = blockIdx.z;
    const int t = threadIdx.x;
#pragma unroll
    for (int rep = 0; rep < 4; ++rep) {
        int i = rep * 256 + t;
        int dl = i >> 4;
        int lq = (i & 15) * 4;
        const float* zp  = xz + ((long)b * 4096 + 2048 + d0 + dl) * 1024 + l0 + lq;
        const float* yfp = y  + ((long)(b)     * 2048 + d0 + dl) * 1024 + l0 + lq;
        const float* ybp = y  + ((long)(2 + b) * 2048 + d0 + dl) * 1024 + (1020 - l0 - lq);
        float4 vz = *(const float4*)zp;
        float4 vf = *(const float4*)yfp;
        float4 vb = *(const float4*)ybp;
        float zz[4]  = {vz.x, vz.y, vz.z, vz.w};
        float ff[4]  = {vf.x, vf.y, vf.z, vf.w};
        float bbv[4] = {vb.w, vb.z, vb.y, vb.x};   // reversed
#pragma unroll
        for (int qq = 0; qq < 4; ++qq) {
            float z = zz[qq];
            float sz = z / (1.f + __builtin_amdgcn_exp2f(-z * 1.44269504f));
            Ls[dl][lq + qq] = sz * (ff[qq] + bbv[qq]);
        }
    }
    __syncthreads();
#pragma unroll
    for (int rep = 0; rep < 4; ++rep) {
        int i = rep * 256 + t;
        int ll = i >> 4;
        int dq = (i & 15) * 4;
        f16x4 h = {(_Float16)Ls[dq][ll], (_Float16)Ls[dq + 1][ll],
                   (_Float16)Ls[dq + 2][ll], (_Float16)Ls[dq + 3][ll]};
        *(f16x4*)(GT + ((long)(b * 1024 + l0 + ll)) * 2048 + d0 + dq) = h;
    }
}

extern "C" void kernel_launch(void* const* d_in, const int* in_sizes, int n_in,
                              void* d_out, int out_size, void* d_ws, size_t ws_size,
                              hipStream_t stream)
{
    const float* hidden   = (const float*)d_in[0];
    const float* inproj_w = (const float*)d_in[1];
    const float* conv_w   = (const float*)d_in[2];
    const float* conv_b   = (const float*)d_in[3];
    const float* xproj_w  = (const float*)d_in[4];
    const float* dtproj_w = (const float*)d_in[5];
    const float* dt_bias  = (const float*)d_in[6];
    const float* A_log    = (const float*)d_in[7];
    const float* D_skip   = (const float*)d_in[8];
    const float* convb_w  = (const float*)d_in[9];
    const float* convb_b  = (const float*)d_in[10];
    const float* xprojb_w = (const float*)d_in[11];
    const float* dtprojb_w= (const float*)d_in[12];
    const float* dtb_bias = (const float*)d_in[13];
    const float* Ab_log   = (const float*)d_in[14];
    const float* Db_skip  = (const float*)d_in[15];
    const float* outproj_w= (const float*)d_in[16];
    float* out = (float*)d_out;

    float* ws    = (float*)d_ws;
    float* xz    = ws;
    float* u     = ws + 8388608;
    float* xdbl  = ws + 16777216;
    float* delta = ws + 17170432;
    float* y     = ws + 25559040;
    // fp16 aliases in temporally-dead regions:
    _Float16* H16    = (_Float16*)u;                 // 4 MB, dead before conv
    _Float16* Win16  = (_Float16*)(u + 1048576);     // 8 MB, dead before conv
    float*    xpb    = delta;                        // x_proj partials (3.1M f32)
    _Float16* GT     = (_Float16*)delta;             // after scan
    _Float16* Wout16 = (_Float16*)y;                 // after combine
    // scratch in y head (dead until scan writes y)
    float*    dwcat  = y;                            // 262144
    float*    bcat   = y + 262144;                   // 4096
    _Float16* xw16   = (_Float16*)(y + 266240);      // 393216 fp16 = 196608 f32

    // 0) f32 -> fp16 conversions (into dead u-region head)
    hipLaunchKernelGGL(cvt_f16_kernel, dim3(2048), dim3(256), 0, stream,
        hidden, H16, 2097152);
    hipLaunchKernelGGL(cvt_f16_kernel, dim3(4096), dim3(256), 0, stream,
        inproj_w, Win16, 4194304);

    // 0b) concat dt weights/bias (f32) + x_proj weights (fp16)
    hipLaunchKernelGGL(concat_weights, dim3(768), dim3(256), 0, stream,
        xproj_w, xprojb_w, dtproj_w, dtprojb_w, dt_bias, dtb_bias,
        xw16, dwcat, bcat);

    // 1) in_proj MFMA: xz[b][e][l]
    hipLaunchKernelGGL((gemm_nt_f16<2, 2, 4, 4>),
        dim3(32, 8, 2), dim3(256), 0, stream,
        H16, Win16, xz, 1024, 1024, 1048576L, 4194304L);

    // 2) conv + silu (overwrites u region incl. H16/Win16)
    hipLaunchKernelGGL(conv_silu_kernel, dim3(32768), dim3(256), 0, stream,
        xz, conv_w, conv_b, convb_w, convb_b, u);

    // 3) x_proj MFMA split-K -> partials in delta region
    hipLaunchKernelGGL(xproj_f16_kernel, dim3(8, XP_SK, 4), dim3(256), 0, stream,
        u, xw16, xpb);
    hipLaunchKernelGGL(xreduce_kernel, dim3(384), dim3(256), 0, stream,
        xpb, xdbl);

    // 4) dt_proj batched f32, softplus(.+bias) epilogue (overwrites partials)
    hipLaunchKernelGGL((gemm_f32<128, 128, 8, 8, true, true>),
        dim3(8, 16, 4), dim3(256), 0, stream,
        dwcat, xdbl, delta, 2048, 1024, 64,
        131072L, (long)96 * 1024, (long)2048 * 1024, bcat);

    // 5) fused selective scan
    hipLaunchKernelGGL(scan_kernel, dim3(128, 2, 2), dim3(256), 0, stream,
        u, delta, xdbl, A_log, Ab_log, D_skip, Db_skip, y);

    // 6) combine -> GT fp16 [b][l][d]
    hipLaunchKernelGGL(combine_T_kernel, dim3(32, 16, 2), dim3(256), 0, stream,
        xz, y, GT);

    // 7) W_out -> fp16 (into y head, after combine consumed y)
    hipLaunchKernelGGL(cvt_f16_kernel, dim3(2048), dim3(256), 0, stream,
        outproj_w, Wout16, 2097152);

    // 8) out_proj MFMA: out[(b,l)][o]
    hipLaunchKernelGGL((gemm_nt_f16<4, 1, 2, 4>),
        dim3(32, 8, 1), dim3(256), 0, stream,
        Wout16, GT, out, 2048, 1024, 0L, 0L);
}